// Round 7
// baseline (84.406 us; speedup 1.0000x reference)
//
#include <hip/hip_runtime.h>
#include <math.h>

#define NW 599
#define NRR 598
#define NT 512

__device__ inline float wave_sum(float v) {
#pragma unroll
  for (int o = 32; o > 0; o >>= 1) v += __shfl_down(v, o);
  return v;
}

__device__ inline float wave_allsum(float v) {
#pragma unroll
  for (int o = 32; o > 0; o >>= 1) v += __shfl_xor(v, o);
  return v;
}

// One 512-thread block per row. Whole row staged to LDS once; all 599
// windows in one pass; single-pass stats (no mean-first dependency) so the
// feature phase has ONE reduction barrier; MLP+LN run entirely in wave 0.
__global__ __launch_bounds__(NT, 8) void prv_fused(
    const float* __restrict__ x, const float* __restrict__ W1,
    const float* __restrict__ b1, const float* __restrict__ W2,
    const float* __restrict__ b2, const float* __restrict__ gamma,
    const float* __restrict__ beta, float* __restrict__ out) {
  __shared__ float s_row[9000];
  __shared__ float s_pk[600];
  __shared__ float s_part[8][28];  // per-wave: [0]=Srr [1]=Srr2 [2]=Sd2 [3..26]=re/im
  __shared__ float s_tot[28];
  __shared__ float s_feat[5];

  const int row = blockIdx.x;
  const int tid = threadIdx.x;
  const int wid = tid >> 6, lane = tid & 63;

  // ---- stage full row (2250 float4, coalesced) ----
  const float4* __restrict__ src = (const float4*)(x + (size_t)row * 9000);
  float4* d4 = (float4*)s_row;
  for (int i = tid; i < 2250; i += NT) d4[i] = src[i];
  __syncthreads();

  // ---- softargmax peaks: window w reads s_row[15w..15w+30) ----
  for (int w = tid; w < NW; w += NT) {
    const float* p = s_row + 15 * w;  // stride 15 (odd) -> <=2-way bank alias
    float m = p[0];
#pragma unroll
    for (int j = 1; j < 30; ++j) m = fmaxf(m, p[j]);
    float se = 0.f, we = 0.f;
#pragma unroll
    for (int j = 0; j < 30; ++j) {
      float e = __expf((p[j] - m) * 10.0f);  // temp = 0.1
      se += e;
      we += (float)j * e;
    }
    s_pk[w] = we / se + 15.0f * (float)w;
  }
  __syncthreads();

  // ---- per-thread single-pass stats over its 1-2 rr values ----
  const float inv30 = 1.0f / 30.0f;
  float Srr = 0.f, Srr2 = 0.f, Sd2 = 0.f;
  float rv0 = 0.f, rv1 = 0.f;
  const int n0 = tid, n1 = tid + NT;
  if (n0 < NRR) {
    rv0 = (s_pk[n0 + 1] - s_pk[n0]) * inv30;
    Srr += rv0;
    Srr2 = fmaf(rv0, rv0, Srr2);
    if (n0 < NRR - 1) {
      float d = (s_pk[n0 + 2] - 2.f * s_pk[n0 + 1] + s_pk[n0]) * inv30;
      Sd2 = fmaf(d, d, Sd2);
    }
  }
  if (n1 < NRR) {
    rv1 = (s_pk[n1 + 1] - s_pk[n1]) * inv30;
    Srr += rv1;
    Srr2 = fmaf(rv1, rv1, Srr2);
    if (n1 < NRR - 1) {
      float d = (s_pk[n1 + 2] - 2.f * s_pk[n1 + 1] + s_pk[n1]) * inv30;
      Sd2 = fmaf(d, d, Sd2);
    }
  }
  Srr = wave_sum(Srr);
  Srr2 = wave_sum(Srr2);
  Sd2 = wave_sum(Sd2);
  if (lane == 0) {
    s_part[wid][0] = Srr;
    s_part[wid][1] = Srr2;
    s_part[wid][2] = Sd2;
  }

  // ---- sparse DFT bins k=2..13 of rfft(rr,1024), reduced bin-by-bin ----
#pragma unroll
  for (int kk = 0; kk < 12; ++kk) {
    const int k = kk + 2;
    const int m0 = (k * n0) & 1023;  // exact integer phase
    const int m1 = (k * n1) & 1023;  // harmless garbage when rv1==0
    float sn0, cs0, sn1, cs1;
    __sincosf((float)m0 * 6.13592315154256491e-3f, &sn0, &cs0);
    __sincosf((float)m1 * 6.13592315154256491e-3f, &sn1, &cs1);
    float rk = rv0 * cs0 + rv1 * cs1;
    float ik = -(rv0 * sn0 + rv1 * sn1);
    rk = wave_sum(rk);
    ik = wave_sum(ik);
    if (lane == 0) {
      s_part[wid][3 + 2 * kk] = rk;
      s_part[wid][4 + 2 * kk] = ik;
    }
  }
  __syncthreads();

  // ---- combine 8 wave-partials ----
  if (tid < 27) {
    float t = 0.f;
#pragma unroll
    for (int w = 0; w < 8; ++w) t += s_part[w][tid];
    s_tot[tid] = t;
  }
  __syncthreads();
  if (tid == 0) {
    const float S = s_tot[0], S2 = s_tot[1], D2 = s_tot[2];
    const float mean = S * (1.0f / (float)NRR);
    const float var = (S2 - (float)NRR * mean * mean) * (1.0f / (float)(NRR - 1));
    float lf = 0.f, hf = 0.f;
#pragma unroll
    for (int kk = 0; kk < 12; ++kk) {
      float r = s_tot[3 + 2 * kk], i2 = s_tot[4 + 2 * kk];
      float pw = r * r + i2 * i2;
      if (kk < 4) lf += pw; else hf += pw;
    }
    s_feat[0] = mean;
    s_feat[1] = sqrtf(D2 * (1.0f / (float)(NRR - 1)) + 1e-6f);  // rmssd
    s_feat[2] = sqrtf(fmaxf(var, 0.f));                          // sdnn
    s_feat[3] = lf;
    s_feat[4] = hf;
  }
  __syncthreads();

  // ---- MLP (5->64->128) + LayerNorm, entirely in wave 0 ----
  if (wid == 0) {
    const float f0 = s_feat[0], f1 = s_feat[1], f2 = s_feat[2],
                f3 = s_feat[3], f4 = s_feat[4];
    float h1 = b1[lane];
    h1 = fmaf(f0, W1[lane], h1);
    h1 = fmaf(f1, W1[64 + lane], h1);
    h1 = fmaf(f2, W1[128 + lane], h1);
    h1 = fmaf(f3, W1[192 + lane], h1);
    h1 = fmaf(f4, W1[256 + lane], h1);
    h1 = fmaxf(h1, 0.f);

    float a0 = b2[lane], a1 = b2[64 + lane];
#pragma unroll 8
    for (int i = 0; i < 64; ++i) {
      float hv = __shfl(h1, i);
      a0 = fmaf(hv, W2[i * 128 + lane], a0);
      a1 = fmaf(hv, W2[i * 128 + 64 + lane], a1);
    }

    const float mu = wave_allsum(a0 + a1) * (1.0f / 128.0f);
    const float var =
        wave_allsum((a0 - mu) * (a0 - mu) + (a1 - mu) * (a1 - mu)) *
        (1.0f / 128.0f);
    const float inv = rsqrtf(var + 1e-5f);
    out[(size_t)row * 128 + lane] = (a0 - mu) * inv * gamma[lane] + beta[lane];
    out[(size_t)row * 128 + 64 + lane] =
        (a1 - mu) * inv * gamma[64 + lane] + beta[64 + lane];
  }
}

extern "C" void kernel_launch(void* const* d_in, const int* in_sizes, int n_in,
                              void* d_out, int out_size, void* d_ws,
                              size_t ws_size, hipStream_t stream) {
  const float* x = (const float*)d_in[0];
  const float* W1 = (const float*)d_in[1];
  const float* b1 = (const float*)d_in[2];
  const float* W2 = (const float*)d_in[3];
  const float* b2 = (const float*)d_in[4];
  const float* gamma = (const float*)d_in[5];
  const float* beta = (const float*)d_in[6];
  float* out = (float*)d_out;

  const int B = in_sizes[0] / 9000;
  prv_fused<<<B, NT, 0, stream>>>(x, W1, b1, W2, b2, gamma, beta, out);
}

// Round 9
// 49.097 us; speedup vs baseline: 1.7192x; 1.7192x over previous
//
#include <hip/hip_runtime.h>
#include <math.h>

#define NW 599
#define NRR 598

__device__ inline float wave_allsum(float v) {
#pragma unroll
  for (int o = 32; o > 0; o >>= 1) v += __shfl_xor(v, o);
  return v;
}

// ---------------- kernel A: peaks, barrier-free ----------------
// One 640-thread block per row = 10 waves. Wave g stages floats
// [960g, 960g+976) (last wave: 360) into its PRIVATE LDS region and computes
// windows 64g..64g+63. Same-wave ds_write->ds_read needs no __syncthreads.
__global__ __launch_bounds__(640, 7) void peaks_kernel(
    const float* __restrict__ x, float* __restrict__ pk) {
  __shared__ float4 s4[2440];  // 10 waves * 244 float4
  const int row = blockIdx.x;
  const int tid = threadIdx.x;
  const int g = tid >> 6, lane = tid & 63;

  const int nf4 = (g < 9) ? 244 : 90;
  const float4* __restrict__ src = (const float4*)x + (size_t)row * 2250 + 240 * g;
  float4* dst = s4 + g * 244;
  for (int j = lane; j < nf4; j += 64) dst[j] = src[j];
  // no barrier: compiler inserts lgkmcnt before dependent ds_reads

  const int w = 64 * g + lane;
  if (w < NW) {
    const float* p = (const float*)(s4 + g * 244) + 15 * lane;  // odd stride
    float m = p[0];
#pragma unroll
    for (int j = 1; j < 30; ++j) m = fmaxf(m, p[j]);
    float se = 0.f, we = 0.f;
#pragma unroll
    for (int j = 0; j < 30; ++j) {
      float e = __expf((p[j] - m) * 10.0f);  // temp = 0.1
      se += e;
      we += (float)j * e;
    }
    pk[(size_t)row * 600 + w] = we / se + 15.0f * (float)w;
  }
}

// ---------------- kernel B: features + MLP + LN, barrier-free ----------------
// One wave per row, 8 rows per 512-thread block. No LDS. Lane l owns rr
// indices [10l, 10l+cnt); stats + 12-bin DFT in registers; butterfly sums.
__global__ __launch_bounds__(512, 6) void feat_kernel(
    const float* __restrict__ pk, const float* __restrict__ W1,
    const float* __restrict__ b1, const float* __restrict__ W2,
    const float* __restrict__ b2, const float* __restrict__ gamma,
    const float* __restrict__ beta, float* __restrict__ out, int nrows) {
  const int tid = threadIdx.x;
  const int wid = tid >> 6, lane = tid & 63;
  const int row = blockIdx.x * 8 + wid;
  if (row >= nrows) return;  // wave-uniform exit

  const float* __restrict__ pkr = pk + (size_t)row * 600;
  const int n0 = lane * 10;
  const int cnt = max(0, min(NRR - n0, 10));  // lanes 0-58:10, 59:8, 60-63:0

  const float inv30 = 1.0f / 30.0f;
  float p[11];
#pragma unroll
  for (int j = 0; j < 11; ++j) p[j] = (j <= cnt && cnt > 0) ? pkr[n0 + j] : 0.f;

  float rr[10];
#pragma unroll
  for (int j = 0; j < 10; ++j)
    rr[j] = (j < cnt) ? (p[j + 1] - p[j]) * inv30 : 0.f;

  // stats
  float Srr = 0.f, Srr2 = 0.f, Sd2 = 0.f;
#pragma unroll
  for (int j = 0; j < 10; ++j) {
    Srr += rr[j];
    Srr2 = fmaf(rr[j], rr[j], Srr2);
    if (j < cnt - 1) {
      float d = rr[j + 1] - rr[j];
      Sd2 = fmaf(d, d, Sd2);
    }
  }
  // boundary diff: n = n0 + cnt - 1, needs neighbor lane's rr[0]
  float nxt0 = __shfl(rr[0], lane + 1);
  if (cnt > 0 && n0 + cnt - 1 <= NRR - 2) {
    float d = nxt0 - rr[cnt - 1];
    Sd2 = fmaf(d, d, Sd2);
  }

  // sparse DFT bins k=2..13 of rfft(rr,1024): base angle + constant-step rotation
  const float c0 = 6.13592315154256491e-3f;  // 2*pi/1024
  float re[12], im[12];
#pragma unroll
  for (int kk = 0; kk < 12; ++kk) {
    const int k = kk + 2;
    float cb, sb, cs, ss;
    __sincosf((float)((k * n0) & 1023) * c0, &sb, &cb);
    __sincosf((float)k * c0, &ss, &cs);
    float r = 0.f, i2 = 0.f;
#pragma unroll
    for (int j = 0; j < 10; ++j) {
      if (j < cnt) {
        r = fmaf(rr[j], cb, r);
        i2 = fmaf(-rr[j], sb, i2);
      }
      float cb2 = cb * cs - sb * ss;  // rotate by step
      sb = fmaf(sb, cs, cb * ss);
      cb = cb2;
    }
    re[kk] = r;
    im[kk] = i2;
  }

  // wave reductions (butterfly -> all lanes hold totals)
  Srr = wave_allsum(Srr);
  Srr2 = wave_allsum(Srr2);
  Sd2 = wave_allsum(Sd2);
  float lf = 0.f, hf = 0.f;
#pragma unroll
  for (int kk = 0; kk < 12; ++kk) {
    float r = wave_allsum(re[kk]);
    float i2 = wave_allsum(im[kk]);
    float pw = fmaf(r, r, i2 * i2);
    if (kk < 4) lf += pw; else hf += pw;
  }

  const float mean = Srr * (1.0f / (float)NRR);
  const float var =
      (Srr2 - (float)NRR * mean * mean) * (1.0f / (float)(NRR - 1));
  const float sdnn = sqrtf(fmaxf(var, 0.f));
  const float rmssd = sqrtf(Sd2 * (1.0f / (float)(NRR - 1)) + 1e-6f);

  // MLP layer 1: h1[lane]
  float h1 = b1[lane];
  h1 = fmaf(mean, W1[lane], h1);
  h1 = fmaf(rmssd, W1[64 + lane], h1);
  h1 = fmaf(sdnn, W1[128 + lane], h1);
  h1 = fmaf(lf, W1[192 + lane], h1);
  h1 = fmaf(hf, W1[256 + lane], h1);
  h1 = fmaxf(h1, 0.f);

  // MLP layer 2: outputs lane and lane+64
  float a0 = b2[lane], a1 = b2[64 + lane];
#pragma unroll 8
  for (int i = 0; i < 64; ++i) {
    float hv = __shfl(h1, i);
    a0 = fmaf(hv, W2[i * 128 + lane], a0);
    a1 = fmaf(hv, W2[i * 128 + 64 + lane], a1);
  }

  // LayerNorm over 128
  const float mu = wave_allsum(a0 + a1) * (1.0f / 128.0f);
  const float vv =
      wave_allsum((a0 - mu) * (a0 - mu) + (a1 - mu) * (a1 - mu)) *
      (1.0f / 128.0f);
  const float inv = rsqrtf(vv + 1e-5f);
  out[(size_t)row * 128 + lane] = (a0 - mu) * inv * gamma[lane] + beta[lane];
  out[(size_t)row * 128 + 64 + lane] =
      (a1 - mu) * inv * gamma[64 + lane] + beta[64 + lane];
}

extern "C" void kernel_launch(void* const* d_in, const int* in_sizes, int n_in,
                              void* d_out, int out_size, void* d_ws,
                              size_t ws_size, hipStream_t stream) {
  const float* x = (const float*)d_in[0];
  const float* W1 = (const float*)d_in[1];
  const float* b1 = (const float*)d_in[2];
  const float* W2 = (const float*)d_in[3];
  const float* b2 = (const float*)d_in[4];
  const float* gamma = (const float*)d_in[5];
  const float* beta = (const float*)d_in[6];
  float* out = (float*)d_out;

  const int B = in_sizes[0] / 9000;
  float* pk = (float*)d_ws;  // B*600 floats = 9.8 MB << ws_size

  peaks_kernel<<<B, 640, 0, stream>>>(x, pk);
  feat_kernel<<<(B + 7) / 8, 512, 0, stream>>>(pk, W1, b1, W2, b2, gamma, beta,
                                               out, B);
}

// Round 10
// 47.856 us; speedup vs baseline: 1.7637x; 1.0259x over previous
//
#include <hip/hip_runtime.h>
#include <math.h>

#define NW 599
#define NRR 598

// async global->LDS DMA, 16 B/lane; LDS dest = wave-uniform base + lane*16
#define GLOAD16(gp, lp)                                                   \
  __builtin_amdgcn_global_load_lds(                                       \
      (const __attribute__((address_space(1))) void*)(gp),                \
      (__attribute__((address_space(3))) void*)(lp), 16, 0, 0)

__device__ inline float wave_allsum(float v) {
#pragma unroll
  for (int o = 32; o > 0; o >>= 1) v += __shfl_xor(v, o);
  return v;
}

// ---------------- kernel A: peaks, barrier-free, async-staged ----------------
// One 640-thread block per row = 10 waves. Wave g owns windows 64g..64g+63,
// i.e. floats [960g, 960g+976). Staging via global_load_lds (4 issues/wave,
// all in flight -> deep HBM stream), then one vmcnt(0) and private ds_reads.
__global__ __launch_bounds__(640) void peaks_kernel(
    const float* __restrict__ x, float* __restrict__ pk) {
  __shared__ float s[9760];  // 10 waves * 976 floats (39 KB)
  const int row = blockIdx.x;
  const int tid = threadIdx.x;
  const int g = tid >> 6, lane = tid & 63;

  const float* __restrict__ src = x + (size_t)row * 9000 + 960 * g;
  float* dstf = s + g * 976;
  const int nfl = (g < 9) ? 976 : 360;  // wave 9: floats [8640,9000)

#pragma unroll
  for (int j = 0; j < 4; ++j) {
    const int f0 = j * 256 + lane * 4;  // this lane's float offset in span
    if (f0 < nfl) GLOAD16(src + f0, dstf + j * 256);
  }
  asm volatile("s_waitcnt vmcnt(0)" ::: "memory");
  // no __syncthreads: each wave reads only its own staged span

  const int w = 64 * g + lane;
  if (w < NW) {
    const float* p = dstf + 15 * lane;  // stride 15 (odd) -> benign aliasing
    float m = p[0];
#pragma unroll
    for (int j = 1; j < 30; ++j) m = fmaxf(m, p[j]);
    float se = 0.f, we = 0.f;
#pragma unroll
    for (int j = 0; j < 30; ++j) {
      float e = __expf((p[j] - m) * 10.0f);  // temp = 0.1
      se += e;
      we += (float)j * e;
    }
    pk[(size_t)row * 600 + w] = we / se + 15.0f * (float)w;
  }
}

// ---------------- kernel B: features + MLP + LN, barrier-free ----------------
// One wave per row, 8 rows per 512-thread block. No LDS. Lane l owns rr
// indices [10l, 10l+cnt); stats + 12-bin DFT in registers; butterfly sums.
__global__ __launch_bounds__(512, 6) void feat_kernel(
    const float* __restrict__ pk, const float* __restrict__ W1,
    const float* __restrict__ b1, const float* __restrict__ W2,
    const float* __restrict__ b2, const float* __restrict__ gamma,
    const float* __restrict__ beta, float* __restrict__ out, int nrows) {
  const int tid = threadIdx.x;
  const int wid = tid >> 6, lane = tid & 63;
  const int row = blockIdx.x * 8 + wid;
  if (row >= nrows) return;  // wave-uniform exit

  const float* __restrict__ pkr = pk + (size_t)row * 600;
  const int n0 = lane * 10;
  const int cnt = max(0, min(NRR - n0, 10));  // lanes 0-58:10, 59:8, 60-63:0

  const float inv30 = 1.0f / 30.0f;
  float p[11];
#pragma unroll
  for (int j = 0; j < 11; ++j) p[j] = (j <= cnt && cnt > 0) ? pkr[n0 + j] : 0.f;

  float rr[10];
#pragma unroll
  for (int j = 0; j < 10; ++j)
    rr[j] = (j < cnt) ? (p[j + 1] - p[j]) * inv30 : 0.f;

  // stats
  float Srr = 0.f, Srr2 = 0.f, Sd2 = 0.f;
#pragma unroll
  for (int j = 0; j < 10; ++j) {
    Srr += rr[j];
    Srr2 = fmaf(rr[j], rr[j], Srr2);
    if (j < cnt - 1) {
      float d = rr[j + 1] - rr[j];
      Sd2 = fmaf(d, d, Sd2);
    }
  }
  // boundary diff needs neighbor lane's rr[0]
  float nxt0 = __shfl(rr[0], lane + 1);
  if (cnt > 0 && n0 + cnt - 1 <= NRR - 2) {
    float d = nxt0 - rr[cnt - 1];
    Sd2 = fmaf(d, d, Sd2);
  }

  // sparse DFT bins k=2..13 of rfft(rr,1024): base angle + constant-step rotation
  const float c0 = 6.13592315154256491e-3f;  // 2*pi/1024
  float re[12], im[12];
#pragma unroll
  for (int kk = 0; kk < 12; ++kk) {
    const int k = kk + 2;
    float cb, sb, cs, ss;
    __sincosf((float)((k * n0) & 1023) * c0, &sb, &cb);
    __sincosf((float)k * c0, &ss, &cs);
    float r = 0.f, i2 = 0.f;
#pragma unroll
    for (int j = 0; j < 10; ++j) {
      if (j < cnt) {
        r = fmaf(rr[j], cb, r);
        i2 = fmaf(-rr[j], sb, i2);
      }
      float cb2 = cb * cs - sb * ss;  // rotate by step
      sb = fmaf(sb, cs, cb * ss);
      cb = cb2;
    }
    re[kk] = r;
    im[kk] = i2;
  }

  // wave reductions (butterfly -> all lanes hold totals)
  Srr = wave_allsum(Srr);
  Srr2 = wave_allsum(Srr2);
  Sd2 = wave_allsum(Sd2);
  float lf = 0.f, hf = 0.f;
#pragma unroll
  for (int kk = 0; kk < 12; ++kk) {
    float r = wave_allsum(re[kk]);
    float i2 = wave_allsum(im[kk]);
    float pw = fmaf(r, r, i2 * i2);
    if (kk < 4) lf += pw; else hf += pw;
  }

  const float mean = Srr * (1.0f / (float)NRR);
  const float var =
      (Srr2 - (float)NRR * mean * mean) * (1.0f / (float)(NRR - 1));
  const float sdnn = sqrtf(fmaxf(var, 0.f));
  const float rmssd = sqrtf(Sd2 * (1.0f / (float)(NRR - 1)) + 1e-6f);

  // MLP layer 1: h1[lane]
  float h1 = b1[lane];
  h1 = fmaf(mean, W1[lane], h1);
  h1 = fmaf(rmssd, W1[64 + lane], h1);
  h1 = fmaf(sdnn, W1[128 + lane], h1);
  h1 = fmaf(lf, W1[192 + lane], h1);
  h1 = fmaf(hf, W1[256 + lane], h1);
  h1 = fmaxf(h1, 0.f);

  // MLP layer 2: outputs lane and lane+64
  float a0 = b2[lane], a1 = b2[64 + lane];
#pragma unroll 8
  for (int i = 0; i < 64; ++i) {
    float hv = __shfl(h1, i);
    a0 = fmaf(hv, W2[i * 128 + lane], a0);
    a1 = fmaf(hv, W2[i * 128 + 64 + lane], a1);
  }

  // LayerNorm over 128
  const float mu = wave_allsum(a0 + a1) * (1.0f / 128.0f);
  const float vv =
      wave_allsum((a0 - mu) * (a0 - mu) + (a1 - mu) * (a1 - mu)) *
      (1.0f / 128.0f);
  const float inv = rsqrtf(vv + 1e-5f);
  out[(size_t)row * 128 + lane] = (a0 - mu) * inv * gamma[lane] + beta[lane];
  out[(size_t)row * 128 + 64 + lane] =
      (a1 - mu) * inv * gamma[64 + lane] + beta[64 + lane];
}

extern "C" void kernel_launch(void* const* d_in, const int* in_sizes, int n_in,
                              void* d_out, int out_size, void* d_ws,
                              size_t ws_size, hipStream_t stream) {
  const float* x = (const float*)d_in[0];
  const float* W1 = (const float*)d_in[1];
  const float* b1 = (const float*)d_in[2];
  const float* W2 = (const float*)d_in[3];
  const float* b2 = (const float*)d_in[4];
  const float* gamma = (const float*)d_in[5];
  const float* beta = (const float*)d_in[6];
  float* out = (float*)d_out;

  const int B = in_sizes[0] / 9000;
  float* pk = (float*)d_ws;  // B*600 floats = 9.8 MB << ws_size

  peaks_kernel<<<B, 640, 0, stream>>>(x, pk);
  feat_kernel<<<(B + 7) / 8, 512, 0, stream>>>(pk, W1, b1, W2, b2, gamma, beta,
                                               out, B);
}